// Round 9
// baseline (109.443 us; speedup 1.0000x reference)
//
#include <hip/hip_runtime.h>
#include <math.h>

static constexpr int BLK = 256;
static constexpr int R = 8;      // queries per thread
static constexpr int TILE = 256; // scan points staged in LDS per block
static constexpr float BIGW = 1e30f;  // finite sentinel

__device__ __forceinline__ unsigned f2u(float f) { return __float_as_uint(f); }
__device__ __forceinline__ float u2f(unsigned u) { return __uint_as_float(u); }

// prep: sentinels + out=0 (288 KB ws).
__global__ void prep_kernel(unsigned long long* __restrict__ o2s,
                            unsigned* __restrict__ s2o,
                            float* __restrict__ out, int N, int M) {
    int i = blockIdx.x * blockDim.x + threadIdx.x;
    if (i < N) o2s[i] = ~0ull;
    if (i < M) s2o[i] = 0xFFFFFFFFu;
    if (i == 0) out[0] = 0.0f;
}

// Fused bidirectional NN scan (scalar VALU; pk_fma regressed R6/R7).
// min over d2 == min over m = 0.5|scan|^2 - qry.scan ; d2 = 2*(0.5|qry|^2 + m)
// __launch_bounds__(BLK,2): raise VGPR budget so p[R]/mmin[R] + staged tile
// points stay register-resident (R8's VGPR_Count=32 implies the allocator was
// chunking the r-loop and re-reading LDS; occupancy is not the binding resource
// in this VALU-bound loop).
__global__ void __launch_bounds__(BLK, 2) main_kernel(
    const float* __restrict__ P, const float* __restrict__ Ps,
    unsigned long long* __restrict__ o2s, unsigned* __restrict__ s2o,
    int N, int M, int o2sX, int o2sBlocks, int s2oX) {
    __shared__ float4 tile[TILE];
    int bx = blockIdx.x;

    if (bx < o2sBlocks) {
        // ---- original -> sampled: queries = P (N), scan = Ps (M), min+argmin ----
        int ix = bx % o2sX, iy = bx / o2sX;
        int ibase = ix * (BLK * R) + threadIdx.x;
        int j0 = iy * TILE;
        float4 p[R];
        float mmin[R];
#pragma unroll
        for (int r = 0; r < R; ++r) {
            int i = ibase + r * BLK;
            float x = 0.f, y = 0.f, z = 0.f;
            if (i < N) { x = P[3 * i]; y = P[3 * i + 1]; z = P[3 * i + 2]; }
            p[r] = make_float4(-x, -y, -z, 0.5f * (x * x + y * y + z * z));
            mmin[r] = __builtin_inff();
        }
        {
            int idx = j0 + threadIdx.x;
            float x = 0.f, y = 0.f, z = 0.f, w = BIGW;
            if (idx < M) {
                x = Ps[3 * idx]; y = Ps[3 * idx + 1]; z = Ps[3 * idx + 2];
                w = 0.5f * (x * x + y * y + z * z);
            }
            tile[threadIdx.x] = make_float4(x, y, z, w);
        }
        __syncthreads();
#pragma unroll 8
        for (int ii = 0; ii < TILE; ii += 2) {
            float4 qa = tile[ii];
            float4 qb = tile[ii + 1];
#pragma unroll
            for (int r = 0; r < R; ++r) {
                float ma = fmaf(qa.x, p[r].x, fmaf(qa.y, p[r].y, fmaf(qa.z, p[r].z, qa.w)));
                float mb = fmaf(qb.x, p[r].x, fmaf(qb.y, p[r].y, fmaf(qb.z, p[r].z, qb.w)));
                float pa = u2f((f2u(ma) & 0xFFFFFF00u) | (unsigned)ii);
                float pb = u2f((f2u(mb) & 0xFFFFFF00u) | (unsigned)(ii + 1));
                mmin[r] = fminf(fminf(mmin[r], pa), pb);  // -> v_min3_f32
            }
        }
#pragma unroll
        for (int r = 0; r < R; ++r) {
            int i = ibase + r * BLK;
            if (i < N) {
                unsigned j = (unsigned)j0 + (f2u(mmin[r]) & 0xFFu);
                float d2 = fmaxf(2.0f * (p[r].w + mmin[r]), 0.0f);
                atomicMin(&o2s[i], ((unsigned long long)f2u(d2) << 32) | j);
            }
        }
    } else {
        // ---- sampled -> original: queries = Ps (M), scan = P (N), min only ----
        int b = bx - o2sBlocks;
        int ix = b % s2oX, iy = b / s2oX;
        int jbase = ix * (BLK * R) + threadIdx.x;
        int i0 = iy * TILE;
        float4 q[R];
        float mmin[R];
#pragma unroll
        for (int r = 0; r < R; ++r) {
            int j = jbase + r * BLK;
            float x = 0.f, y = 0.f, z = 0.f;
            if (j < M) { x = Ps[3 * j]; y = Ps[3 * j + 1]; z = Ps[3 * j + 2]; }
            q[r] = make_float4(-x, -y, -z, 0.5f * (x * x + y * y + z * z));
            mmin[r] = __builtin_inff();
        }
        {
            int idx = i0 + threadIdx.x;
            float x = 0.f, y = 0.f, z = 0.f, w = BIGW;
            if (idx < N) {
                x = P[3 * idx]; y = P[3 * idx + 1]; z = P[3 * idx + 2];
                w = 0.5f * (x * x + y * y + z * z);
            }
            tile[threadIdx.x] = make_float4(x, y, z, w);
        }
        __syncthreads();
#pragma unroll 8
        for (int ii = 0; ii < TILE; ii += 2) {
            float4 pa = tile[ii];
            float4 pb = tile[ii + 1];
#pragma unroll
            for (int r = 0; r < R; ++r) {
                float ma = fmaf(pa.x, q[r].x, fmaf(pa.y, q[r].y, fmaf(pa.z, q[r].z, pa.w)));
                float mb = fmaf(pb.x, q[r].x, fmaf(pb.y, q[r].y, fmaf(pb.z, q[r].z, pb.w)));
                mmin[r] = fminf(fminf(mmin[r], ma), mb);  // -> v_min3_f32
            }
        }
#pragma unroll
        for (int r = 0; r < R; ++r) {
            int j = jbase + r * BLK;
            if (j < M) {
                float d2 = fmaxf(2.0f * (q[r].w + mmin[r]), 0.0f);
                atomicMin(&s2o[j], f2u(d2));
            }
        }
    }
}

// finish: one load per query, weight, block-reduce, one atomicAdd per block.
__global__ void finish_kernel(const unsigned* __restrict__ s2o,
                              const unsigned long long* __restrict__ o2s,
                              const float* __restrict__ prob,
                              float* __restrict__ out, int N, int M) {
    int t = blockIdx.x * BLK + threadIdx.x;
    float acc = 0.0f;
    if (t < M) {
        acc = sqrtf(u2f(s2o[t])) * prob[t];
    } else if (t < M + N) {
        unsigned long long key = o2s[t - M];
        float d2 = u2f((unsigned)(key >> 32));
        unsigned jj = (unsigned)(key & 0xFFFFFFFFu);
        acc = sqrtf(d2) * prob[jj];
    }
#pragma unroll
    for (int off = 32; off > 0; off >>= 1) acc += __shfl_down(acc, off, 64);
    __shared__ float wsum[BLK / 64];
    int lane = threadIdx.x & 63, wave = threadIdx.x >> 6;
    if (lane == 0) wsum[wave] = acc;
    __syncthreads();
    if (threadIdx.x == 0) {
        float s = 0.0f;
#pragma unroll
        for (int w = 0; w < BLK / 64; ++w) s += wsum[w];
        atomicAdd(out, s);
    }
}

extern "C" void kernel_launch(void* const* d_in, const int* in_sizes, int n_in,
                              void* d_out, int out_size, void* d_ws, size_t ws_size,
                              hipStream_t stream) {
    const float* P = (const float*)d_in[0];
    const float* Ps = (const float*)d_in[1];
    const float* prob = (const float*)d_in[2];
    int N = in_sizes[0] / 3;  // 32768
    int M = in_sizes[1] / 3;  // 8192
    float* out = (float*)d_out;

    unsigned long long* o2s = (unsigned long long*)d_ws;       // N * 8 B
    unsigned* s2o = (unsigned*)((char*)d_ws + (size_t)N * 8);  // M * 4 B

    int o2sX = (N + BLK * R - 1) / (BLK * R);   // 16
    int o2sY = (M + TILE - 1) / TILE;           // 32
    int s2oX = (M + BLK * R - 1) / (BLK * R);   // 4
    int s2oY = (N + TILE - 1) / TILE;           // 128
    int o2sBlocks = o2sX * o2sY;                // 512
    int total = o2sBlocks + s2oX * s2oY;        // 1024 = 4 blocks/CU launched

    prep_kernel<<<(N + BLK - 1) / BLK, BLK, 0, stream>>>(o2s, s2o, out, N, M);
    main_kernel<<<total, BLK, 0, stream>>>(P, Ps, o2s, s2o, N, M,
                                           o2sX, o2sBlocks, s2oX);
    finish_kernel<<<(N + M + BLK - 1) / BLK, BLK, 0, stream>>>(s2o, o2s, prob,
                                                               out, N, M);
}

// Round 10
// 107.036 us; speedup vs baseline: 1.0225x; 1.0225x over previous
//
#include <hip/hip_runtime.h>
#include <math.h>

static constexpr int BLK = 256;
static constexpr int R = 4;      // queries per thread (R=4 -> 2048 blocks = 8/CU)
static constexpr int TILE = 256; // scan points staged in LDS per block
static constexpr float BIGW = 1e30f;  // finite sentinel

__device__ __forceinline__ unsigned f2u(float f) { return __float_as_uint(f); }
__device__ __forceinline__ float u2f(unsigned u) { return __uint_as_float(u); }

// prep: sentinels + out=0 (288 KB ws).
__global__ void prep_kernel(unsigned long long* __restrict__ o2s,
                            unsigned* __restrict__ s2o,
                            float* __restrict__ out, int N, int M) {
    int i = blockIdx.x * blockDim.x + threadIdx.x;
    if (i < N) o2s[i] = ~0ull;
    if (i < M) s2o[i] = 0xFFFFFFFFu;
    if (i == 0) out[0] = 0.0f;
}

// Fused bidirectional NN scan.
// min over d2 == min over m = 0.5|scan|^2 - qry.scan ; d2 = 2*(0.5|qry|^2 + m)
// R=4: grid 2048 blocks -> 8 blocks/CU, 32 waves/CU. R8/R9 showed real VALU
// busy ~50% (VALUBusy~110% is the gfx94x SIMD-16 formula, 2x overcount on
// gfx950) at 16 waves/CU cap -> latency-stall-bound, so buy occupancy with
// grid size, not fewer instructions.
__global__ void __launch_bounds__(BLK) main_kernel(
    const float* __restrict__ P, const float* __restrict__ Ps,
    unsigned long long* __restrict__ o2s, unsigned* __restrict__ s2o,
    int N, int M, int o2sX, int o2sBlocks, int s2oX) {
    __shared__ float4 tile[TILE];
    int bx = blockIdx.x;

    if (bx < o2sBlocks) {
        // ---- original -> sampled: queries = P (N), scan = Ps (M), min+argmin ----
        int ix = bx % o2sX, iy = bx / o2sX;
        int ibase = ix * (BLK * R) + threadIdx.x;
        int j0 = iy * TILE;
        float4 p[R];
        float mmin[R];
#pragma unroll
        for (int r = 0; r < R; ++r) {
            int i = ibase + r * BLK;
            float x = 0.f, y = 0.f, z = 0.f;
            if (i < N) { x = P[3 * i]; y = P[3 * i + 1]; z = P[3 * i + 2]; }
            p[r] = make_float4(-x, -y, -z, 0.5f * (x * x + y * y + z * z));
            mmin[r] = __builtin_inff();
        }
        {
            int idx = j0 + threadIdx.x;
            float x = 0.f, y = 0.f, z = 0.f, w = BIGW;
            if (idx < M) {
                x = Ps[3 * idx]; y = Ps[3 * idx + 1]; z = Ps[3 * idx + 2];
                w = 0.5f * (x * x + y * y + z * z);
            }
            tile[threadIdx.x] = make_float4(x, y, z, w);
        }
        __syncthreads();
#pragma unroll 8
        for (int ii = 0; ii < TILE; ii += 2) {
            float4 qa = tile[ii];
            float4 qb = tile[ii + 1];
#pragma unroll
            for (int r = 0; r < R; ++r) {
                float ma = fmaf(qa.x, p[r].x, fmaf(qa.y, p[r].y, fmaf(qa.z, p[r].z, qa.w)));
                float mb = fmaf(qb.x, p[r].x, fmaf(qb.y, p[r].y, fmaf(qb.z, p[r].z, qb.w)));
                float pa = u2f((f2u(ma) & 0xFFFFFF00u) | (unsigned)ii);
                float pb = u2f((f2u(mb) & 0xFFFFFF00u) | (unsigned)(ii + 1));
                mmin[r] = fminf(fminf(mmin[r], pa), pb);  // -> v_min3_f32
            }
        }
#pragma unroll
        for (int r = 0; r < R; ++r) {
            int i = ibase + r * BLK;
            if (i < N) {
                unsigned j = (unsigned)j0 + (f2u(mmin[r]) & 0xFFu);
                float d2 = fmaxf(2.0f * (p[r].w + mmin[r]), 0.0f);
                atomicMin(&o2s[i], ((unsigned long long)f2u(d2) << 32) | j);
            }
        }
    } else {
        // ---- sampled -> original: queries = Ps (M), scan = P (N), min only ----
        int b = bx - o2sBlocks;
        int ix = b % s2oX, iy = b / s2oX;
        int jbase = ix * (BLK * R) + threadIdx.x;
        int i0 = iy * TILE;
        float4 q[R];
        float mmin[R];
#pragma unroll
        for (int r = 0; r < R; ++r) {
            int j = jbase + r * BLK;
            float x = 0.f, y = 0.f, z = 0.f;
            if (j < M) { x = Ps[3 * j]; y = Ps[3 * j + 1]; z = Ps[3 * j + 2]; }
            q[r] = make_float4(-x, -y, -z, 0.5f * (x * x + y * y + z * z));
            mmin[r] = __builtin_inff();
        }
        {
            int idx = i0 + threadIdx.x;
            float x = 0.f, y = 0.f, z = 0.f, w = BIGW;
            if (idx < N) {
                x = P[3 * idx]; y = P[3 * idx + 1]; z = P[3 * idx + 2];
                w = 0.5f * (x * x + y * y + z * z);
            }
            tile[threadIdx.x] = make_float4(x, y, z, w);
        }
        __syncthreads();
#pragma unroll 8
        for (int ii = 0; ii < TILE; ii += 2) {
            float4 pa = tile[ii];
            float4 pb = tile[ii + 1];
#pragma unroll
            for (int r = 0; r < R; ++r) {
                float ma = fmaf(pa.x, q[r].x, fmaf(pa.y, q[r].y, fmaf(pa.z, q[r].z, pa.w)));
                float mb = fmaf(pb.x, q[r].x, fmaf(pb.y, q[r].y, fmaf(pb.z, q[r].z, pb.w)));
                mmin[r] = fminf(fminf(mmin[r], ma), mb);  // -> v_min3_f32
            }
        }
#pragma unroll
        for (int r = 0; r < R; ++r) {
            int j = jbase + r * BLK;
            if (j < M) {
                float d2 = fmaxf(2.0f * (q[r].w + mmin[r]), 0.0f);
                atomicMin(&s2o[j], f2u(d2));
            }
        }
    }
}

// finish: one load per query, weight, block-reduce, one atomicAdd per block.
__global__ void finish_kernel(const unsigned* __restrict__ s2o,
                              const unsigned long long* __restrict__ o2s,
                              const float* __restrict__ prob,
                              float* __restrict__ out, int N, int M) {
    int t = blockIdx.x * BLK + threadIdx.x;
    float acc = 0.0f;
    if (t < M) {
        acc = sqrtf(u2f(s2o[t])) * prob[t];
    } else if (t < M + N) {
        unsigned long long key = o2s[t - M];
        float d2 = u2f((unsigned)(key >> 32));
        unsigned jj = (unsigned)(key & 0xFFFFFFFFu);
        acc = sqrtf(d2) * prob[jj];
    }
#pragma unroll
    for (int off = 32; off > 0; off >>= 1) acc += __shfl_down(acc, off, 64);
    __shared__ float wsum[BLK / 64];
    int lane = threadIdx.x & 63, wave = threadIdx.x >> 6;
    if (lane == 0) wsum[wave] = acc;
    __syncthreads();
    if (threadIdx.x == 0) {
        float s = 0.0f;
#pragma unroll
        for (int w = 0; w < BLK / 64; ++w) s += wsum[w];
        atomicAdd(out, s);
    }
}

extern "C" void kernel_launch(void* const* d_in, const int* in_sizes, int n_in,
                              void* d_out, int out_size, void* d_ws, size_t ws_size,
                              hipStream_t stream) {
    const float* P = (const float*)d_in[0];
    const float* Ps = (const float*)d_in[1];
    const float* prob = (const float*)d_in[2];
    int N = in_sizes[0] / 3;  // 32768
    int M = in_sizes[1] / 3;  // 8192
    float* out = (float*)d_out;

    unsigned long long* o2s = (unsigned long long*)d_ws;       // N * 8 B
    unsigned* s2o = (unsigned*)((char*)d_ws + (size_t)N * 8);  // M * 4 B

    int o2sX = (N + BLK * R - 1) / (BLK * R);   // 32
    int o2sY = (M + TILE - 1) / TILE;           // 32
    int s2oX = (M + BLK * R - 1) / (BLK * R);   // 8
    int s2oY = (N + TILE - 1) / TILE;           // 128
    int o2sBlocks = o2sX * o2sY;                // 1024
    int total = o2sBlocks + s2oX * s2oY;        // 2048 = 8 blocks/CU

    prep_kernel<<<(N + BLK - 1) / BLK, BLK, 0, stream>>>(o2s, s2o, out, N, M);
    main_kernel<<<total, BLK, 0, stream>>>(P, Ps, o2s, s2o, N, M,
                                           o2sX, o2sBlocks, s2oX);
    finish_kernel<<<(N + M + BLK - 1) / BLK, BLK, 0, stream>>>(s2o, o2s, prob,
                                                               out, N, M);
}

// Round 11
// 106.569 us; speedup vs baseline: 1.0270x; 1.0044x over previous
//
#include <hip/hip_runtime.h>
#include <math.h>

static constexpr int BLK = 256;
static constexpr int R = 8;      // queries per thread (LDS reads/pair = 1/R)
static constexpr int TILE = 128; // scan points per LDS tile (keeps grid at 2048)
static constexpr float BIGW = 1e30f;  // finite sentinel

__device__ __forceinline__ unsigned f2u(float f) { return __float_as_uint(f); }
__device__ __forceinline__ float u2f(unsigned u) { return __uint_as_float(u); }

// prep: sentinels + out=0 (288 KB ws).
__global__ void prep_kernel(unsigned long long* __restrict__ o2s,
                            unsigned* __restrict__ s2o,
                            float* __restrict__ out, int N, int M) {
    int i = blockIdx.x * blockDim.x + threadIdx.x;
    if (i < N) o2s[i] = ~0ull;
    if (i < M) s2o[i] = 0xFFFFFFFFu;
    if (i == 0) out[0] = 0.0f;
}

// Fused bidirectional NN scan.
// min over d2 == min over m = 0.5|scan|^2 - qry.scan ; d2 = 2*(0.5|qry|^2 + m)
// Pipe accounting (R10 post-mortem): ds_read_b128 total = 8.39M/R; R=4 put
// ~41us on the LDS pipe vs 27us VALU -> LDS-bound. R=8 halves LDS traffic;
// TILE=128 keeps 2048 blocks (8/CU, 32 waves/CU). One point per iteration:
// the 2-point body made the allocator split the r-loop (VGPR 32) and re-read
// the tile, doubling LDS traffic (R8/R9 evidence).
__global__ void __launch_bounds__(BLK) main_kernel(
    const float* __restrict__ P, const float* __restrict__ Ps,
    unsigned long long* __restrict__ o2s, unsigned* __restrict__ s2o,
    int N, int M, int o2sX, int o2sBlocks, int s2oX) {
    __shared__ float4 tile[TILE];
    int bx = blockIdx.x;

    if (bx < o2sBlocks) {
        // ---- original -> sampled: queries = P (N), scan = Ps (M), min+argmin ----
        int ix = bx % o2sX, iy = bx / o2sX;
        int ibase = ix * (BLK * R) + threadIdx.x;
        int j0 = iy * TILE;
        float4 p[R];
        float mmin[R];
#pragma unroll
        for (int r = 0; r < R; ++r) {
            int i = ibase + r * BLK;
            float x = 0.f, y = 0.f, z = 0.f;
            if (i < N) { x = P[3 * i]; y = P[3 * i + 1]; z = P[3 * i + 2]; }
            p[r] = make_float4(-x, -y, -z, 0.5f * (x * x + y * y + z * z));
            mmin[r] = __builtin_inff();
        }
        if (threadIdx.x < TILE) {
            int idx = j0 + threadIdx.x;
            float x = 0.f, y = 0.f, z = 0.f, w = BIGW;
            if (idx < M) {
                x = Ps[3 * idx]; y = Ps[3 * idx + 1]; z = Ps[3 * idx + 2];
                w = 0.5f * (x * x + y * y + z * z);
            }
            tile[threadIdx.x] = make_float4(x, y, z, w);
        }
        __syncthreads();
#pragma unroll 8
        for (int ii = 0; ii < TILE; ++ii) {
            float4 q = tile[ii];
#pragma unroll
            for (int r = 0; r < R; ++r) {
                float m = fmaf(q.x, p[r].x, fmaf(q.y, p[r].y, fmaf(q.z, p[r].z, q.w)));
                float mp = u2f((f2u(m) & 0xFFFFFF00u) | (unsigned)ii);
                mmin[r] = fminf(mmin[r], mp);
            }
        }
#pragma unroll
        for (int r = 0; r < R; ++r) {
            int i = ibase + r * BLK;
            if (i < N) {
                unsigned j = (unsigned)j0 + (f2u(mmin[r]) & 0xFFu);
                float d2 = fmaxf(2.0f * (p[r].w + mmin[r]), 0.0f);
                atomicMin(&o2s[i], ((unsigned long long)f2u(d2) << 32) | j);
            }
        }
    } else {
        // ---- sampled -> original: queries = Ps (M), scan = P (N), min only ----
        int b = bx - o2sBlocks;
        int ix = b % s2oX, iy = b / s2oX;
        int jbase = ix * (BLK * R) + threadIdx.x;
        int i0 = iy * TILE;
        float4 q[R];
        float mmin[R];
#pragma unroll
        for (int r = 0; r < R; ++r) {
            int j = jbase + r * BLK;
            float x = 0.f, y = 0.f, z = 0.f;
            if (j < M) { x = Ps[3 * j]; y = Ps[3 * j + 1]; z = Ps[3 * j + 2]; }
            q[r] = make_float4(-x, -y, -z, 0.5f * (x * x + y * y + z * z));
            mmin[r] = __builtin_inff();
        }
        if (threadIdx.x < TILE) {
            int idx = i0 + threadIdx.x;
            float x = 0.f, y = 0.f, z = 0.f, w = BIGW;
            if (idx < N) {
                x = P[3 * idx]; y = P[3 * idx + 1]; z = P[3 * idx + 2];
                w = 0.5f * (x * x + y * y + z * z);
            }
            tile[threadIdx.x] = make_float4(x, y, z, w);
        }
        __syncthreads();
#pragma unroll 8
        for (int ii = 0; ii < TILE; ++ii) {
            float4 pt = tile[ii];
#pragma unroll
            for (int r = 0; r < R; ++r) {
                float m = fmaf(pt.x, q[r].x, fmaf(pt.y, q[r].y, fmaf(pt.z, q[r].z, pt.w)));
                mmin[r] = fminf(mmin[r], m);
            }
        }
#pragma unroll
        for (int r = 0; r < R; ++r) {
            int j = jbase + r * BLK;
            if (j < M) {
                float d2 = fmaxf(2.0f * (q[r].w + mmin[r]), 0.0f);
                atomicMin(&s2o[j], f2u(d2));
            }
        }
    }
}

// finish: one load per query, weight, block-reduce, one atomicAdd per block.
__global__ void finish_kernel(const unsigned* __restrict__ s2o,
                              const unsigned long long* __restrict__ o2s,
                              const float* __restrict__ prob,
                              float* __restrict__ out, int N, int M) {
    int t = blockIdx.x * BLK + threadIdx.x;
    float acc = 0.0f;
    if (t < M) {
        acc = sqrtf(u2f(s2o[t])) * prob[t];
    } else if (t < M + N) {
        unsigned long long key = o2s[t - M];
        float d2 = u2f((unsigned)(key >> 32));
        unsigned jj = (unsigned)(key & 0xFFFFFFFFu);
        acc = sqrtf(d2) * prob[jj];
    }
#pragma unroll
    for (int off = 32; off > 0; off >>= 1) acc += __shfl_down(acc, off, 64);
    __shared__ float wsum[BLK / 64];
    int lane = threadIdx.x & 63, wave = threadIdx.x >> 6;
    if (lane == 0) wsum[wave] = acc;
    __syncthreads();
    if (threadIdx.x == 0) {
        float s = 0.0f;
#pragma unroll
        for (int w = 0; w < BLK / 64; ++w) s += wsum[w];
        atomicAdd(out, s);
    }
}

extern "C" void kernel_launch(void* const* d_in, const int* in_sizes, int n_in,
                              void* d_out, int out_size, void* d_ws, size_t ws_size,
                              hipStream_t stream) {
    const float* P = (const float*)d_in[0];
    const float* Ps = (const float*)d_in[1];
    const float* prob = (const float*)d_in[2];
    int N = in_sizes[0] / 3;  // 32768
    int M = in_sizes[1] / 3;  // 8192
    float* out = (float*)d_out;

    unsigned long long* o2s = (unsigned long long*)d_ws;       // N * 8 B
    unsigned* s2o = (unsigned*)((char*)d_ws + (size_t)N * 8);  // M * 4 B

    int o2sX = (N + BLK * R - 1) / (BLK * R);   // 16
    int o2sY = (M + TILE - 1) / TILE;           // 64
    int s2oX = (M + BLK * R - 1) / (BLK * R);   // 4
    int s2oY = (N + TILE - 1) / TILE;           // 256
    int o2sBlocks = o2sX * o2sY;                // 1024
    int total = o2sBlocks + s2oX * s2oY;        // 2048 = 8 blocks/CU

    prep_kernel<<<(N + BLK - 1) / BLK, BLK, 0, stream>>>(o2s, s2o, out, N, M);
    main_kernel<<<total, BLK, 0, stream>>>(P, Ps, o2s, s2o, N, M,
                                           o2sX, o2sBlocks, s2oX);
    finish_kernel<<<(N + M + BLK - 1) / BLK, BLK, 0, stream>>>(s2o, o2s, prob,
                                                               out, N, M);
}